// Round 9
// baseline (309.291 us; speedup 1.0000x reference)
//
#include <hip/hip_runtime.h>
#include <math.h>

typedef __bf16 bf16x8 __attribute__((ext_vector_type(8)));
typedef __bf16 bf16x4 __attribute__((ext_vector_type(4)));
typedef float  f32x4  __attribute__((ext_vector_type(4)));
typedef unsigned int u32x4 __attribute__((ext_vector_type(4)));

#define B_   2
#define N_   4096
#define D_   512
#define H_   8
#define FF_  2048
#define BN_  (B_*N_)
static constexpr float SCALE_ = 0.04419417382415922f;  // 512^-0.5
static constexpr float LOG2E_ = 1.44269504088896341f;
static constexpr float SCALE_L2E_ = SCALE_ * LOG2E_;   // fold log2e into Q scale

#define GLOAD_LDS16(g, l) __builtin_amdgcn_global_load_lds( \
    (const __attribute__((address_space(1))) void*)(g),     \
    (__attribute__((address_space(3))) void*)(l), 16, 0, 0)

// ---------------- weight transpose f32[R][C] -> bf16[C][R] ----------------
__global__ void transpose_to_bf16(const float* __restrict__ in, __bf16* __restrict__ out,
                                  int R, int C) {
    __shared__ float tile[32][33];
    const int c0 = blockIdx.x * 32, r0 = blockIdx.y * 32;
    const int tx = threadIdx.x, ty = threadIdx.y;   // (32,8)
#pragma unroll
    for (int i = 0; i < 4; ++i)
        tile[ty + 8*i][tx] = in[(size_t)(r0 + ty + 8*i) * C + c0 + tx];
    __syncthreads();
#pragma unroll
    for (int i = 0; i < 4; ++i)
        out[(size_t)(c0 + ty + 8*i) * R + r0 + tx] = (__bf16)tile[tx][ty + 8*i];
}

// ---------------- f32 -> bf16 elementwise (dist), folds log2e ----------------
__global__ void cvt_bf16(const float* __restrict__ in, __bf16* __restrict__ out, int n4) {
    int i = blockIdx.x * blockDim.x + threadIdx.x;
    const int stride = gridDim.x * blockDim.x;
    for (; i < n4; i += stride) {
        float4 v = ((const float4*)in)[i];
        bf16x4 o;
        o[0] = (__bf16)(v.x * LOG2E_); o[1] = (__bf16)(v.y * LOG2E_);
        o[2] = (__bf16)(v.z * LOG2E_); o[3] = (__bf16)(v.w * LOG2E_);
        ((bf16x4*)out)[i] = o;
    }
}

// ---------------- LayerNorm f32 -> bf16, one row (512) per block of 128 ----------------
__global__ __launch_bounds__(128)
void ln_kernel(const float* __restrict__ x, const float* __restrict__ w,
               const float* __restrict__ b, __bf16* __restrict__ out) {
    const int row = blockIdx.x, t = threadIdx.x;
    const float4 v = *(const float4*)&x[(size_t)row * 512 + t * 4];
    float s  = v.x + v.y + v.z + v.w;
    float sq = v.x*v.x + v.y*v.y + v.z*v.z + v.w*v.w;
#pragma unroll
    for (int mk = 1; mk < 64; mk <<= 1) { s += __shfl_xor(s, mk); sq += __shfl_xor(sq, mk); }
    __shared__ float ps[2][2];
    if ((t & 63) == 0) { ps[t >> 6][0] = s; ps[t >> 6][1] = sq; }
    __syncthreads();
    s = ps[0][0] + ps[1][0]; sq = ps[0][1] + ps[1][1];
    const float mu  = s * (1.0f / 512.0f);
    const float var = sq * (1.0f / 512.0f) - mu * mu;
    const float rs  = rsqrtf(var + 1e-5f);
    const float4 wv = *(const float4*)&w[t * 4];
    const float4 bv = *(const float4*)&b[t * 4];
    bf16x4 o;
    o[0] = (__bf16)((v.x - mu) * rs * wv.x + bv.x);
    o[1] = (__bf16)((v.y - mu) * rs * wv.y + bv.y);
    o[2] = (__bf16)((v.z - mu) * rs * wv.z + bv.z);
    o[3] = (__bf16)((v.w - mu) * rs * wv.w + bv.w);
    *(bf16x4*)&out[(size_t)row * 512 + t * 4] = o;
}

// ---------------- bf16 GEMM, C = A[M,K] * Bt[N,K]^T, fused epilogues ----------------
// EPI 0: +bias -> bf16 | EPI 1: +bias, exact gelu -> bf16 | EPI 2: +bias +resid(f32) -> f32
template<int EPI, int BNT>
__global__ __launch_bounds__(256)
void gemm_bt(const __bf16* __restrict__ A, const __bf16* __restrict__ Bt,
             const float* __restrict__ bias, const float* __restrict__ resid,
             __bf16* __restrict__ outb, float* __restrict__ outf,
             int M, int N, int K) {
    constexpr int NI = BNT / 32;                  // n-frags per wave (4 or 2)
    __shared__ __align__(16) __bf16 As[128 * 64];
    __shared__ __align__(16) __bf16 Bs[BNT * 64];
    const int tid = threadIdx.x;
    const int w = tid >> 6, l = tid & 63;
    const int g = l >> 4, c = l & 15;
    const int m0 = blockIdx.y * 128, n0 = blockIdx.x * BNT;
    const int wm = (w >> 1) * 64, wn = (w & 1) * (BNT / 2);
    f32x4 acc[4][NI] = {};

    for (int kt = 0; kt < K; kt += 64) {
        __syncthreads();
#pragma unroll
        for (int i = 0; i < 4; ++i) {             // A tile: 128x64
            const int cb = (i * 4 + w) * 64;      // wave-uniform chunk base
            const int chunk = cb + l;
            const int row = chunk >> 3, c8 = chunk & 7;
            GLOAD_LDS16(A + (size_t)(m0 + row) * K + kt + c8 * 8, As + cb * 8);
        }
#pragma unroll
        for (int i = 0; i < BNT / 32; ++i) {      // B tile: BNTx64
            const int cb = (i * 4 + w) * 64;
            const int chunk = cb + l;
            const int row = chunk >> 3, c8 = chunk & 7;
            GLOAD_LDS16(Bt + (size_t)(n0 + row) * K + kt + c8 * 8, Bs + cb * 8);
        }
        __syncthreads();
#pragma unroll
        for (int kk = 0; kk < 2; ++kk) {
            bf16x8 av[4], bv[NI];
#pragma unroll
            for (int mi = 0; mi < 4; ++mi)
                av[mi] = *(const bf16x8*)&As[(wm + mi * 16 + c) * 64 + kk * 32 + g * 8];
#pragma unroll
            for (int ni = 0; ni < NI; ++ni)
                bv[ni] = *(const bf16x8*)&Bs[(wn + ni * 16 + c) * 64 + kk * 32 + g * 8];
#pragma unroll
            for (int mi = 0; mi < 4; ++mi)
#pragma unroll
                for (int ni = 0; ni < NI; ++ni)
                    acc[mi][ni] = __builtin_amdgcn_mfma_f32_16x16x32_bf16(
                        av[mi], bv[ni], acc[mi][ni], 0, 0, 0);
        }
    }
#pragma unroll
    for (int mi = 0; mi < 4; ++mi)
#pragma unroll
        for (int ni = 0; ni < NI; ++ni)
#pragma unroll
            for (int r = 0; r < 4; ++r) {
                const int row = m0 + wm + mi * 16 + g * 4 + r;
                const int col = n0 + wn + ni * 16 + c;
                float v = acc[mi][ni][r] + bias[col];
                const size_t oidx = (size_t)row * N + col;
                if constexpr (EPI == 0) {
                    outb[oidx] = (__bf16)v;
                } else if constexpr (EPI == 1) {
                    outb[oidx] = (__bf16)(0.5f * v * (1.0f + erff(v * 0.70710678118654752f)));
                } else {
                    outf[oidx] = v + resid[oidx];
                }
            }
}

// ---------------- flash attention: ONE barrier per kt-iteration ----------------
// 128 q-rows/block, 512 blocks = 2/CU, fused finalize. Ks/Vts/DPs ALL double-
// buffered (66KB LDS) -> per-iter schedule has a single __syncthreads and no
// asm waits (r6/r7 proved prefetch tuning around the 2-barrier structure is
// null; the barriers themselves were the fixed cost):
//   iter kt (cur=kt&1): everything for kt already resident.
//   1. issue K/dist(kt+1) -> [cur^1] gloads, V(kt+1) -> vreg  (fly whole iter)
//   2. QK^T + fused softmax  (Ks[cur], DPs[cur]) -> pa regs
//   3. PV                     (Vts[cur])
//   4. V^T(kt+1) ds-writes -> Vts[cur^1]   (no conflict with step 3's [cur])
//   5. __syncthreads  (drains vmcnt+lgkmcnt: prefetches landed, reads done)
// Hazards: every buffer written in iter kt is first read in iter kt+1; every
// buffer read in iter kt is first overwritten in iter kt+1 -- all resolved at
// the single barrier.
__global__ __launch_bounds__(256, 2)
void attn_kernel(const __bf16* __restrict__ qkv, const __bf16* __restrict__ distb,
                 const float* __restrict__ gamma, __bf16* __restrict__ outp) {
    __shared__ __align__(16) __bf16 Ks [2][64 * 64];   // K, linear + XOR swizzle
    __shared__ __align__(16) __bf16 Vts[2][64][72];    // V^T, k XOR-swizzled
    __shared__ __align__(16) __bf16 DPs[2][128 * 64];  // dist, linear + XOR swizzle
    const int tid = threadIdx.x;
    const int w = tid >> 6, l = tid & 63;
    const int g = l >> 4, c = l & 15;
    const int qt = blockIdx.x, h = blockIdx.y;
    const int b = blockIdx.z;
    const float gb = gamma[b];
    const size_t tok0 = (size_t)b * N_;
    const int qrow = 16 * w + c;                    // lane's local q row (group 0)
    const int wub = tid & 192;                      // w*64, wave-uniform lds chunk base
    const int srow = tid >> 3;                      // staging row (0..31)
    const int sd0  = (tid & 7) * 8;                 // staging d-offset

    // Q fragments for both groups, pre-scaled by SCALE*log2e
    bf16x8 qf[2][2];
#pragma unroll
    for (int t = 0; t < 2; ++t) {
        const size_t qbase = (tok0 + qt * 128 + 64 * t + qrow) * 1536 + h * 64;
#pragma unroll
        for (int kk = 0; kk < 2; ++kk) {
            const bf16x8 qv = *(const bf16x8*)&qkv[qbase + kk * 32 + g * 8];
#pragma unroll
            for (int j = 0; j < 8; ++j) qf[t][kk][j] = (__bf16)((float)qv[j] * SCALE_L2E_);
        }
    }

    f32x4 acc[2][4] = {};   // acc[t][di][r] = Onum[q=64t+qrow][d=16di+4g+r]
    float lsum[2] = {0.f, 0.f};
    bf16x8 vreg[2];

    auto issue_k = [&](int kt, int buf) {
#pragma unroll
        for (int i = 0; i < 2; ++i) {
            const int lin = i * 256 + tid;
            const int row = lin >> 3;
            const int col = ((tid & 7) ^ (row & 7)) * 8;   // source pre-swizzle
            GLOAD_LDS16(qkv + 512 + (tok0 + (size_t)kt * 64 + row) * 1536 + h * 64 + col,
                        Ks[buf] + (i * 256 + wub) * 8);
        }
    };
    auto issue_d = [&](int kt, int buf) {
#pragma unroll
        for (int i = 0; i < 4; ++i) {
            const int lin = i * 256 + tid;
            const int row = lin >> 3;
            const int col = ((tid & 7) ^ (row & 7)) * 8;   // source pre-swizzle
            GLOAD_LDS16(distb + (size_t)(qt * 128 + row) * N_ + kt * 64 + col,
                        DPs[buf] + (i * 256 + wub) * 8);
        }
    };
    auto issue_v = [&](int kt) {
#pragma unroll
        for (int rr = 0; rr < 2; ++rr) {
            const int r = srow + 32 * rr;
            vreg[rr] = *(const bf16x8*)
                &qkv[1024 + (tok0 + (size_t)kt * 64 + r) * 1536 + h * 64 + sd0];
        }
    };
    auto write_vts = [&](int buf) {   // scalar transpose: vreg -> Vts[buf]
#pragma unroll
        for (int rr = 0; rr < 2; ++rr) {
            const int r = srow + 32 * rr;
            const int kp = r ^ sd0;   // sd0 = (sd0>>3)<<3 here
#pragma unroll
            for (int j = 0; j < 8; ++j) Vts[buf][sd0 + j][kp] = vreg[rr][j];
        }
    };

    const int ktend = N_ / 64;                      // 64 tiles, all keys
    // prologue: tile 0 -> buffer 0 (vreg ds-write waits on its own vmcnt)
    issue_k(0, 0);
    issue_d(0, 0);
    issue_v(0);
    write_vts(0);
    __syncthreads();    // full drain: tile 0 resident everywhere

    for (int kt = 0; kt < ktend; ++kt) {
        const int cur = kt & 1;
        if (kt + 1 < ktend) {        // prefetches fly across the whole iteration
            issue_k(kt + 1, cur ^ 1);
            issue_d(kt + 1, cur ^ 1);
            issue_v(kt + 1);
        }

        // QK^T + fused softmax per ni (Ks[cur], DPs[cur] resident)
        uint32_t W[2][4][2];
#pragma unroll
        for (int ni = 0; ni < 4; ++ni) {
            f32x4 s0 = {}, s1 = {};
#pragma unroll
            for (int kk = 0; kk < 2; ++kk) {
                const bf16x8 kf = *(const bf16x8*)
                    &Ks[cur][((16 * ni + c) << 6) + ((kk * 32 + g * 8) ^ ((c & 7) << 3))];
                s0 = __builtin_amdgcn_mfma_f32_16x16x32_bf16(kf, qf[0][kk], s0, 0, 0, 0);
                s1 = __builtin_amdgcn_mfma_f32_16x16x32_bf16(kf, qf[1][kk], s1, 0, 0, 0);
            }
#pragma unroll
            for (int t = 0; t < 2; ++t) {
                const int row = 64 * t + qrow;
                const bf16x4 dd = *(const bf16x4*)
                    &DPs[cur][(row << 6) + ((16 * ni + 4 * g) ^ ((c & 7) << 3))];
                const f32x4 sv = (t == 0) ? s0 : s1;
                float pv0, pv1, pv2, pv3;
                pv0 = __builtin_amdgcn_exp2f(fmaf(-gb, (float)dd[0], sv[0]));
                pv1 = __builtin_amdgcn_exp2f(fmaf(-gb, (float)dd[1], sv[1]));
                pv2 = __builtin_amdgcn_exp2f(fmaf(-gb, (float)dd[2], sv[2]));
                pv3 = __builtin_amdgcn_exp2f(fmaf(-gb, (float)dd[3], sv[3]));
                lsum[t] += (pv0 + pv1) + (pv2 + pv3);
                asm("v_cvt_pk_bf16_f32 %0, %1, %2" : "=v"(W[t][ni][0]) : "v"(pv0), "v"(pv1));
                asm("v_cvt_pk_bf16_f32 %0, %1, %2" : "=v"(W[t][ni][1]) : "v"(pv2), "v"(pv3));
            }
        }
        // P-word exchange: permlane32+16 swaps -> PV B-frag words (P never in LDS)
        bf16x8 pa[2][2];
#pragma unroll
        for (int t = 0; t < 2; ++t) {
#pragma unroll
            for (int p = 0; p < 2; ++p)
#pragma unroll
                for (int q2 = 0; q2 < 2; ++q2) {
                    asm("v_permlane32_swap_b32 %0, %1"
                        : "+v"(W[t][2 * q2][p]), "+v"(W[t][2 * q2 + 1][p]));
                    asm("v_permlane16_swap_b32 %0, %1"
                        : "+v"(W[t][2 * q2][p]), "+v"(W[t][2 * q2 + 1][p]));
                }
#pragma unroll
            for (int kk = 0; kk < 2; ++kk) {
                const u32x4 words = {W[t][2 * kk][0], W[t][2 * kk][1],
                                     W[t][2 * kk + 1][0], W[t][2 * kk + 1][1]};
                pa[t][kk] = __builtin_bit_cast(bf16x8, words);
            }
        }

        // O^T += Vt * P^T for both groups, sharing each vb fragment (Vts[cur])
#pragma unroll
        for (int kk = 0; kk < 2; ++kk) {
#pragma unroll
            for (int di = 0; di < 4; ++di) {
                const int d = 16 * di + c;
                const int kp = (kk * 32 + g * 8) ^ ((d >> 3) << 3);
                const bf16x8 vb = *(const bf16x8*)&Vts[cur][d][kp];
                acc[0][di] = __builtin_amdgcn_mfma_f32_16x16x32_bf16(vb, pa[0][kk], acc[0][di], 0, 0, 0);
                acc[1][di] = __builtin_amdgcn_mfma_f32_16x16x32_bf16(vb, pa[1][kk], acc[1][di], 0, 0, 0);
            }
        }

        // stage V^T(kt+1) into the other buffer (no conflict with PV's [cur] reads)
        if (kt + 1 < ktend) write_vts(cur ^ 1);
        __syncthreads();   // single per-iter barrier: drains all vm+lgkm
    }
    // fused finalize: l across the 4 g-lanes sharing each q row; O = acc/l -> bf16
#pragma unroll
    for (int t = 0; t < 2; ++t) {
        lsum[t] += __shfl_xor(lsum[t], 16);
        lsum[t] += __shfl_xor(lsum[t], 32);
        const float rl = 1.0f / lsum[t];
        const int q = qt * 128 + 64 * t + qrow;
#pragma unroll
        for (int di = 0; di < 4; ++di) {
            bf16x4 o;
#pragma unroll
            for (int r = 0; r < 4; ++r) o[r] = (__bf16)(acc[t][di][r] * rl);
            *(bf16x4*)&outp[((size_t)(b * N_ + q)) * 512 + h * 64 + 16 * di + 4 * g] = o;
        }
    }
}

// ---------------- launch ----------------
extern "C" void kernel_launch(void* const* d_in, const int* in_sizes, int n_in,
                              void* d_out, int out_size, void* d_ws, size_t ws_size,
                              hipStream_t stream) {
    (void)in_sizes; (void)n_in; (void)out_size; (void)ws_size;
    const float* x      = (const float*)d_in[0];
    const float* gamma  = (const float*)d_in[1];
    const float* dist   = (const float*)d_in[2];
    const float* ln1_w  = (const float*)d_in[3];
    const float* ln1_b  = (const float*)d_in[4];
    const float* qkv_w  = (const float*)d_in[5];
    const float* qkv_b  = (const float*)d_in[6];
    const float* proj_w = (const float*)d_in[7];
    const float* proj_b = (const float*)d_in[8];
    const float* ln2_w  = (const float*)d_in[9];
    const float* ln2_b  = (const float*)d_in[10];
    const float* fc1_w  = (const float*)d_in[11];
    const float* fc1_b  = (const float*)d_in[12];
    const float* fc2_w  = (const float*)d_in[13];
    const float* fc2_b  = (const float*)d_in[14];
    float* out = (float*)d_out;

    char* ws = (char*)d_ws;
    size_t off = 0;
    auto alloc = [&](size_t bytes) {
        void* p = ws + off; off = (off + bytes + 255) & ~(size_t)255; return p;
    };
    __bf16* distbf  = (__bf16*)alloc((size_t)N_ * N_ * 2);
    __bf16* qkv_wt  = (__bf16*)alloc((size_t)1536 * 512 * 2);
    __bf16* proj_wt = (__bf16*)alloc((size_t)512 * 512 * 2);
    __bf16* fc1_wt  = (__bf16*)alloc((size_t)2048 * 512 * 2);
    __bf16* fc2_wt  = (__bf16*)alloc((size_t)512 * 2048 * 2);
    __bf16* hbuf    = (__bf16*)alloc((size_t)BN_ * 512 * 2);
    __bf16* qkvbuf  = (__bf16*)alloc((size_t)BN_ * 1536 * 2);
    __bf16* attnbuf = (__bf16*)alloc((size_t)BN_ * 512 * 2);
    float*  x1buf   = (float*) alloc((size_t)BN_ * 512 * 4);
    __bf16* h2buf   = (__bf16*)alloc((size_t)BN_ * 512 * 2);
    __bf16* ffbuf   = (__bf16*)alloc((size_t)BN_ * 2048 * 2);

    const dim3 tb(32, 8);
    transpose_to_bf16<<<dim3(1536/32,  512/32), tb, 0, stream>>>(qkv_w,  qkv_wt,  512, 1536);
    transpose_to_bf16<<<dim3( 512/32,  512/32), tb, 0, stream>>>(proj_w, proj_wt, 512,  512);
    transpose_to_bf16<<<dim3(2048/32,  512/32), tb, 0, stream>>>(fc1_w,  fc1_wt,  512, 2048);
    transpose_to_bf16<<<dim3( 512/32, 2048/32), tb, 0, stream>>>(fc2_w,  fc2_wt, 2048,  512);
    cvt_bf16<<<2048, 256, 0, stream>>>(dist, distbf, N_ * N_ / 4);

    ln_kernel<<<BN_, 128, 0, stream>>>(x, ln1_w, ln1_b, hbuf);
    gemm_bt<0,128><<<dim3(1536/128, BN_/128), 256, 0, stream>>>(
        hbuf, qkv_wt, qkv_b, nullptr, qkvbuf, nullptr, BN_, 1536, 512);
    attn_kernel<<<dim3(32, 8, 2), 256, 0, stream>>>(qkvbuf, distbf, gamma, attnbuf);
    gemm_bt<2,64><<<dim3(512/64, BN_/128), 256, 0, stream>>>(
        attnbuf, proj_wt, proj_b, x, nullptr, x1buf, BN_, 512, 512);
    ln_kernel<<<BN_, 128, 0, stream>>>(x1buf, ln2_w, ln2_b, h2buf);
    gemm_bt<1,128><<<dim3(2048/128, BN_/128), 256, 0, stream>>>(
        h2buf, fc1_wt, fc1_b, nullptr, ffbuf, nullptr, BN_, 2048, 512);
    gemm_bt<2,64><<<dim3(512/64, BN_/128), 256, 0, stream>>>(
        ffbuf, fc2_wt, fc2_b, x1buf, nullptr, out, BN_, 512, 2048);
}

// Round 10
// 301.123 us; speedup vs baseline: 1.0271x; 1.0271x over previous
//
#include <hip/hip_runtime.h>
#include <math.h>

typedef __bf16 bf16x8 __attribute__((ext_vector_type(8)));
typedef __bf16 bf16x4 __attribute__((ext_vector_type(4)));
typedef float  f32x4  __attribute__((ext_vector_type(4)));
typedef unsigned int u32x4 __attribute__((ext_vector_type(4)));

#define B_   2
#define N_   4096
#define D_   512
#define H_   8
#define FF_  2048
#define BN_  (B_*N_)
static constexpr float SCALE_ = 0.04419417382415922f;  // 512^-0.5
static constexpr float LOG2E_ = 1.44269504088896341f;
static constexpr float SCALE_L2E_ = SCALE_ * LOG2E_;   // fold log2e into Q scale

#define GLOAD_LDS16(g, l) __builtin_amdgcn_global_load_lds( \
    (const __attribute__((address_space(1))) void*)(g),     \
    (__attribute__((address_space(3))) void*)(l), 16, 0, 0)

// ---------------- weight transpose f32[R][C] -> bf16[C][R] ----------------
__global__ void transpose_to_bf16(const float* __restrict__ in, __bf16* __restrict__ out,
                                  int R, int C) {
    __shared__ float tile[32][33];
    const int c0 = blockIdx.x * 32, r0 = blockIdx.y * 32;
    const int tx = threadIdx.x, ty = threadIdx.y;   // (32,8)
#pragma unroll
    for (int i = 0; i < 4; ++i)
        tile[ty + 8*i][tx] = in[(size_t)(r0 + ty + 8*i) * C + c0 + tx];
    __syncthreads();
#pragma unroll
    for (int i = 0; i < 4; ++i)
        out[(size_t)(c0 + ty + 8*i) * R + r0 + tx] = (__bf16)tile[tx][ty + 8*i];
}

// ---------------- f32 -> bf16 elementwise (dist), folds log2e ----------------
__global__ void cvt_bf16(const float* __restrict__ in, __bf16* __restrict__ out, int n4) {
    int i = blockIdx.x * blockDim.x + threadIdx.x;
    const int stride = gridDim.x * blockDim.x;
    for (; i < n4; i += stride) {
        float4 v = ((const float4*)in)[i];
        bf16x4 o;
        o[0] = (__bf16)(v.x * LOG2E_); o[1] = (__bf16)(v.y * LOG2E_);
        o[2] = (__bf16)(v.z * LOG2E_); o[3] = (__bf16)(v.w * LOG2E_);
        ((bf16x4*)out)[i] = o;
    }
}

// ---------------- LayerNorm f32 -> bf16, one row (512) per block of 128 ----------------
__global__ __launch_bounds__(128)
void ln_kernel(const float* __restrict__ x, const float* __restrict__ w,
               const float* __restrict__ b, __bf16* __restrict__ out) {
    const int row = blockIdx.x, t = threadIdx.x;
    const float4 v = *(const float4*)&x[(size_t)row * 512 + t * 4];
    float s  = v.x + v.y + v.z + v.w;
    float sq = v.x*v.x + v.y*v.y + v.z*v.z + v.w*v.w;
#pragma unroll
    for (int mk = 1; mk < 64; mk <<= 1) { s += __shfl_xor(s, mk); sq += __shfl_xor(sq, mk); }
    __shared__ float ps[2][2];
    if ((t & 63) == 0) { ps[t >> 6][0] = s; ps[t >> 6][1] = sq; }
    __syncthreads();
    s = ps[0][0] + ps[1][0]; sq = ps[0][1] + ps[1][1];
    const float mu  = s * (1.0f / 512.0f);
    const float var = sq * (1.0f / 512.0f) - mu * mu;
    const float rs  = rsqrtf(var + 1e-5f);
    const float4 wv = *(const float4*)&w[t * 4];
    const float4 bv = *(const float4*)&b[t * 4];
    bf16x4 o;
    o[0] = (__bf16)((v.x - mu) * rs * wv.x + bv.x);
    o[1] = (__bf16)((v.y - mu) * rs * wv.y + bv.y);
    o[2] = (__bf16)((v.z - mu) * rs * wv.z + bv.z);
    o[3] = (__bf16)((v.w - mu) * rs * wv.w + bv.w);
    *(bf16x4*)&out[(size_t)row * 512 + t * 4] = o;
}

// ---------------- bf16 GEMM, C = A[M,K] * Bt[N,K]^T, fused epilogues ----------------
// EPI 0: +bias -> bf16 | EPI 1: +bias, exact gelu -> bf16 | EPI 2: +bias +resid(f32) -> f32
template<int EPI, int BNT>
__global__ __launch_bounds__(256)
void gemm_bt(const __bf16* __restrict__ A, const __bf16* __restrict__ Bt,
             const float* __restrict__ bias, const float* __restrict__ resid,
             __bf16* __restrict__ outb, float* __restrict__ outf,
             int M, int N, int K) {
    constexpr int NI = BNT / 32;                  // n-frags per wave (4 or 2)
    __shared__ __align__(16) __bf16 As[128 * 64];
    __shared__ __align__(16) __bf16 Bs[BNT * 64];
    const int tid = threadIdx.x;
    const int w = tid >> 6, l = tid & 63;
    const int g = l >> 4, c = l & 15;
    const int m0 = blockIdx.y * 128, n0 = blockIdx.x * BNT;
    const int wm = (w >> 1) * 64, wn = (w & 1) * (BNT / 2);
    f32x4 acc[4][NI] = {};

    for (int kt = 0; kt < K; kt += 64) {
        __syncthreads();
#pragma unroll
        for (int i = 0; i < 4; ++i) {             // A tile: 128x64
            const int cb = (i * 4 + w) * 64;      // wave-uniform chunk base
            const int chunk = cb + l;
            const int row = chunk >> 3, c8 = chunk & 7;
            GLOAD_LDS16(A + (size_t)(m0 + row) * K + kt + c8 * 8, As + cb * 8);
        }
#pragma unroll
        for (int i = 0; i < BNT / 32; ++i) {      // B tile: BNTx64
            const int cb = (i * 4 + w) * 64;
            const int chunk = cb + l;
            const int row = chunk >> 3, c8 = chunk & 7;
            GLOAD_LDS16(Bt + (size_t)(n0 + row) * K + kt + c8 * 8, Bs + cb * 8);
        }
        __syncthreads();
#pragma unroll
        for (int kk = 0; kk < 2; ++kk) {
            bf16x8 av[4], bv[NI];
#pragma unroll
            for (int mi = 0; mi < 4; ++mi)
                av[mi] = *(const bf16x8*)&As[(wm + mi * 16 + c) * 64 + kk * 32 + g * 8];
#pragma unroll
            for (int ni = 0; ni < NI; ++ni)
                bv[ni] = *(const bf16x8*)&Bs[(wn + ni * 16 + c) * 64 + kk * 32 + g * 8];
#pragma unroll
            for (int mi = 0; mi < 4; ++mi)
#pragma unroll
                for (int ni = 0; ni < NI; ++ni)
                    acc[mi][ni] = __builtin_amdgcn_mfma_f32_16x16x32_bf16(
                        av[mi], bv[ni], acc[mi][ni], 0, 0, 0);
        }
    }
#pragma unroll
    for (int mi = 0; mi < 4; ++mi)
#pragma unroll
        for (int ni = 0; ni < NI; ++ni)
#pragma unroll
            for (int r = 0; r < 4; ++r) {
                const int row = m0 + wm + mi * 16 + g * 4 + r;
                const int col = n0 + wn + ni * 16 + c;
                float v = acc[mi][ni][r] + bias[col];
                const size_t oidx = (size_t)row * N + col;
                if constexpr (EPI == 0) {
                    outb[oidx] = (__bf16)v;
                } else if constexpr (EPI == 1) {
                    outb[oidx] = (__bf16)(0.5f * v * (1.0f + erff(v * 0.70710678118654752f)));
                } else {
                    outf[oidx] = v + resid[oidx];
                }
            }
}

// ---------------- flash attention: swapped operands, 2 q-groups/wave ----------------
// r7 base (proven best & clean: FETCH 86MB, no spills; 128 q-rows, 512 blocks
// = 2/CU, 256-reg budget, fused finalize, DPs double-buffered, no vmcnt at B3).
// r5/r7/r9 established the kernel is instruction-issue-bound, not barrier-bound
// (fewer barriers made it SLOWER). This rev deletes instructions:
//  * lsum via ones-MFMA: l[q] = sum_k P[k][q] computed as mfma(ones, pa, accl)
//    on the matrix pipe -- removes 64 serial v_adds/thread-iter + the final
//    cross-lane shfl reduction. D[.][col=c] = full-k sum for q=c (same q this
//    lane owns in the PV accumulator).
//  * T5 s_setprio(1) around the MFMA clusters (QK kk-pair, PV loop): 2
//    independently-phased blocks/CU = the regime where setprio paid on attn.
__global__ __launch_bounds__(256, 2)
void attn_kernel(const __bf16* __restrict__ qkv, const __bf16* __restrict__ distb,
                 const float* __restrict__ gamma, __bf16* __restrict__ outp) {
    __shared__ __align__(16) __bf16 Ks [64 * 64];      // K tile, linear + XOR swizzle
    __shared__ __align__(16) __bf16 Vts[64][72];       // V transposed, k XOR-swizzled
    __shared__ __align__(16) __bf16 DPs[2][128 * 64];  // dist double-buffer
    const int tid = threadIdx.x;
    const int w = tid >> 6, l = tid & 63;
    const int g = l >> 4, c = l & 15;
    const int qt = blockIdx.x, h = blockIdx.y;
    const int b = blockIdx.z;
    const float gb = gamma[b];
    const size_t tok0 = (size_t)b * N_;
    const int qrow = 16 * w + c;                    // lane's local q row (group 0)
    const int wub = tid & 192;                      // w*64, wave-uniform lds chunk base
    const int srow = tid >> 3;                      // staging row (0..31)
    const int sd0  = (tid & 7) * 8;                 // staging d-offset

    // Q fragments for both groups, pre-scaled by SCALE*log2e
    bf16x8 qf[2][2];
#pragma unroll
    for (int t = 0; t < 2; ++t) {
        const size_t qbase = (tok0 + qt * 128 + 64 * t + qrow) * 1536 + h * 64;
#pragma unroll
        for (int kk = 0; kk < 2; ++kk) {
            const bf16x8 qv = *(const bf16x8*)&qkv[qbase + kk * 32 + g * 8];
#pragma unroll
            for (int j = 0; j < 8; ++j) qf[t][kk][j] = (__bf16)((float)qv[j] * SCALE_L2E_);
        }
    }
    bf16x8 ones;
#pragma unroll
    for (int j = 0; j < 8; ++j) ones[j] = (__bf16)1.0f;

    f32x4 acc[2][4] = {};   // acc[t][di][r] = Onum[q=64t+qrow][d=16di+4g+r]
    f32x4 accl[2] = {};     // accl[t][r] = l[q=64t+qrow] (all r identical)
    bf16x8 vreg[2];

    auto issue_k = [&](int kt) {
#pragma unroll
        for (int i = 0; i < 2; ++i) {
            const int lin = i * 256 + tid;
            const int row = lin >> 3;
            const int col = ((tid & 7) ^ (row & 7)) * 8;   // source pre-swizzle
            GLOAD_LDS16(qkv + 512 + (tok0 + (size_t)kt * 64 + row) * 1536 + h * 64 + col,
                        Ks + (i * 256 + wub) * 8);
        }
    };
    auto issue_d = [&](int kt, int buf) {
#pragma unroll
        for (int i = 0; i < 4; ++i) {
            const int lin = i * 256 + tid;
            const int row = lin >> 3;
            const int col = ((tid & 7) ^ (row & 7)) * 8;   // source pre-swizzle
            GLOAD_LDS16(distb + (size_t)(qt * 128 + row) * N_ + kt * 64 + col,
                        DPs[buf] + (i * 256 + wub) * 8);
        }
    };
    auto issue_v = [&](int kt) {
#pragma unroll
        for (int rr = 0; rr < 2; ++rr) {
            const int r = srow + 32 * rr;
            vreg[rr] = *(const bf16x8*)
                &qkv[1024 + (tok0 + (size_t)kt * 64 + r) * 1536 + h * 64 + sd0];
        }
    };

    const int ktend = N_ / 64;                      // 64 tiles, all keys
    issue_k(0);
    issue_v(0);
    issue_d(0, 0);

    for (int kt = 0; kt < ktend; ++kt) {
        const int cur = kt & 1;
        __syncthreads();     // B1: full drain -- K/V/dist(kt) landed, PV(kt-1) done
        // stage V^T (scalar transpose) from prefetched regs
#pragma unroll
        for (int rr = 0; rr < 2; ++rr) {
            const int r = srow + 32 * rr;
            const int kp = r ^ sd0;    // sd0 = (sd0>>3)<<3 here
#pragma unroll
            for (int j = 0; j < 8; ++j) Vts[sd0 + j][kp] = vreg[rr][j];
        }
        if (kt + 1 < ktend) {    // vreg dead, DPs[cur^1] dead since B3(kt-1):
            issue_v(kt + 1);     // both prefetches get the full-iteration window
            issue_d(kt + 1, cur ^ 1);
        }
        __builtin_amdgcn_sched_barrier(0);

        // QK^T + fused softmax per ni: dd from DPs[cur] (landed at B1)
        uint32_t W[2][4][2];
#pragma unroll
        for (int ni = 0; ni < 4; ++ni) {
            f32x4 s0 = {}, s1 = {};
            __builtin_amdgcn_s_setprio(1);
#pragma unroll
            for (int kk = 0; kk < 2; ++kk) {
                const bf16x8 kf = *(const bf16x8*)
                    &Ks[((16 * ni + c) << 6) + ((kk * 32 + g * 8) ^ ((c & 7) << 3))];
                s0 = __builtin_amdgcn_mfma_f32_16x16x32_bf16(kf, qf[0][kk], s0, 0, 0, 0);
                s1 = __builtin_amdgcn_mfma_f32_16x16x32_bf16(kf, qf[1][kk], s1, 0, 0, 0);
            }
            __builtin_amdgcn_s_setprio(0);
#pragma unroll
            for (int t = 0; t < 2; ++t) {
                const int row = 64 * t + qrow;
                const bf16x4 dd = *(const bf16x4*)
                    &DPs[cur][(row << 6) + ((16 * ni + 4 * g) ^ ((c & 7) << 3))];
                const f32x4 sv = (t == 0) ? s0 : s1;
                float pv0, pv1, pv2, pv3;
                pv0 = __builtin_amdgcn_exp2f(fmaf(-gb, (float)dd[0], sv[0]));
                pv1 = __builtin_amdgcn_exp2f(fmaf(-gb, (float)dd[1], sv[1]));
                pv2 = __builtin_amdgcn_exp2f(fmaf(-gb, (float)dd[2], sv[2]));
                pv3 = __builtin_amdgcn_exp2f(fmaf(-gb, (float)dd[3], sv[3]));
                asm("v_cvt_pk_bf16_f32 %0, %1, %2" : "=v"(W[t][ni][0]) : "v"(pv0), "v"(pv1));
                asm("v_cvt_pk_bf16_f32 %0, %1, %2" : "=v"(W[t][ni][1]) : "v"(pv2), "v"(pv3));
            }
        }
        // P-word exchange: lane(g',c) holds P[q=c][k=16ni+4g'+..]; permlane32+16
        // swaps produce the PV B-frag words k={32kk+8g+2m}. P never touches LDS.
        bf16x8 pa[2][2];
#pragma unroll
        for (int t = 0; t < 2; ++t) {
#pragma unroll
            for (int p = 0; p < 2; ++p)
#pragma unroll
                for (int q2 = 0; q2 < 2; ++q2) {
                    asm("v_permlane32_swap_b32 %0, %1"
                        : "+v"(W[t][2 * q2][p]), "+v"(W[t][2 * q2 + 1][p]));
                    asm("v_permlane16_swap_b32 %0, %1"
                        : "+v"(W[t][2 * q2][p]), "+v"(W[t][2 * q2 + 1][p]));
                }
#pragma unroll
            for (int kk = 0; kk < 2; ++kk) {
                const u32x4 words = {W[t][2 * kk][0], W[t][2 * kk][1],
                                     W[t][2 * kk + 1][0], W[t][2 * kk + 1][1]};
                pa[t][kk] = __builtin_bit_cast(bf16x8, words);
            }
        }
        __builtin_amdgcn_sched_barrier(0);
        // B3: own LDS ops drained (Ks/DPs reads, Vts writes) + block barrier.
        // NO vmcnt wait -- prefetches keep flying.
        asm volatile("s_waitcnt lgkmcnt(0)\n\ts_barrier" ::: "memory");
        __builtin_amdgcn_sched_barrier(0);
        if (kt + 1 < ktend) issue_k(kt + 1);   // Ks free now; flies across PV

        // O^T += Vt * P^T for both groups, sharing each vb fragment.
        // accl += ones * P^T gives the softmax denominator on the matrix pipe.
        __builtin_amdgcn_s_setprio(1);
#pragma unroll
        for (int kk = 0; kk < 2; ++kk) {
            accl[0] = __builtin_amdgcn_mfma_f32_16x16x32_bf16(ones, pa[0][kk], accl[0], 0, 0, 0);
            accl[1] = __builtin_amdgcn_mfma_f32_16x16x32_bf16(ones, pa[1][kk], accl[1], 0, 0, 0);
#pragma unroll
            for (int di = 0; di < 4; ++di) {
                const int d = 16 * di + c;
                const int kp = (kk * 32 + g * 8) ^ ((d >> 3) << 3);
                const bf16x8 vb = *(const bf16x8*)&Vts[d][kp];
                acc[0][di] = __builtin_amdgcn_mfma_f32_16x16x32_bf16(vb, pa[0][kk], acc[0][di], 0, 0, 0);
                acc[1][di] = __builtin_amdgcn_mfma_f32_16x16x32_bf16(vb, pa[1][kk], acc[1][di], 0, 0, 0);
            }
        }
        __builtin_amdgcn_s_setprio(0);
    }
    // fused finalize: accl[t][0] = full softmax denominator; O = acc/l -> bf16
#pragma unroll
    for (int t = 0; t < 2; ++t) {
        const float rl = 1.0f / accl[t][0];
        const int q = qt * 128 + 64 * t + qrow;
#pragma unroll
        for (int di = 0; di < 4; ++di) {
            bf16x4 o;
#pragma unroll
            for (int r = 0; r < 4; ++r) o[r] = (__bf16)(acc[t][di][r] * rl);
            *(bf16x4*)&outp[((size_t)(b * N_ + q)) * 512 + h * 64 + 16 * di + 4 * g] = o;
        }
    }
}

// ---------------- launch ----------------
extern "C" void kernel_launch(void* const* d_in, const int* in_sizes, int n_in,
                              void* d_out, int out_size, void* d_ws, size_t ws_size,
                              hipStream_t stream) {
    (void)in_sizes; (void)n_in; (void)out_size; (void)ws_size;
    const float* x      = (const float*)d_in[0];
    const float* gamma  = (const float*)d_in[1];
    const float* dist   = (const float*)d_in[2];
    const float* ln1_w  = (const float*)d_in[3];
    const float* ln1_b  = (const float*)d_in[4];
    const float* qkv_w  = (const float*)d_in[5];
    const float* qkv_b  = (const float*)d_in[6];
    const float* proj_w = (const float*)d_in[7];
    const float* proj_b = (const float*)d_in[8];
    const float* ln2_w  = (const float*)d_in[9];
    const float* ln2_b  = (const float*)d_in[10];
    const float* fc1_w  = (const float*)d_in[11];
    const float* fc1_b  = (const float*)d_in[12];
    const float* fc2_w  = (const float*)d_in[13];
    const float* fc2_b  = (const float*)d_in[14];
    float* out = (float*)d_out;

    char* ws = (char*)d_ws;
    size_t off = 0;
    auto alloc = [&](size_t bytes) {
        void* p = ws + off; off = (off + bytes + 255) & ~(size_t)255; return p;
    };
    __bf16* distbf  = (__bf16*)alloc((size_t)N_ * N_ * 2);
    __bf16* qkv_wt  = (__bf16*)alloc((size_t)1536 * 512 * 2);
    __bf16* proj_wt = (__bf16*)alloc((size_t)512 * 512 * 2);
    __bf16* fc1_wt  = (__bf16*)alloc((size_t)2048 * 512 * 2);
    __bf16* fc2_wt  = (__bf16*)alloc((size_t)512 * 2048 * 2);
    __bf16* hbuf    = (__bf16*)alloc((size_t)BN_ * 512 * 2);
    __bf16* qkvbuf  = (__bf16*)alloc((size_t)BN_ * 1536 * 2);
    __bf16* attnbuf = (__bf16*)alloc((size_t)BN_ * 512 * 2);
    float*  x1buf   = (float*) alloc((size_t)BN_ * 512 * 4);
    __bf16* h2buf   = (__bf16*)alloc((size_t)BN_ * 512 * 2);
    __bf16* ffbuf   = (__bf16*)alloc((size_t)BN_ * 2048 * 2);

    const dim3 tb(32, 8);
    transpose_to_bf16<<<dim3(1536/32,  512/32), tb, 0, stream>>>(qkv_w,  qkv_wt,  512, 1536);
    transpose_to_bf16<<<dim3( 512/32,  512/32), tb, 0, stream>>>(proj_w, proj_wt, 512,  512);
    transpose_to_bf16<<<dim3(2048/32,  512/32), tb, 0, stream>>>(fc1_w,  fc1_wt,  512, 2048);
    transpose_to_bf16<<<dim3( 512/32, 2048/32), tb, 0, stream>>>(fc2_w,  fc2_wt, 2048,  512);
    cvt_bf16<<<2048, 256, 0, stream>>>(dist, distbf, N_ * N_ / 4);

    ln_kernel<<<BN_, 128, 0, stream>>>(x, ln1_w, ln1_b, hbuf);
    gemm_bt<0,128><<<dim3(1536/128, BN_/128), 256, 0, stream>>>(
        hbuf, qkv_wt, qkv_b, nullptr, qkvbuf, nullptr, BN_, 1536, 512);
    attn_kernel<<<dim3(32, 8, 2), 256, 0, stream>>>(qkvbuf, distbf, gamma, attnbuf);
    gemm_bt<2,64><<<dim3(512/64, BN_/128), 256, 0, stream>>>(
        attnbuf, proj_wt, proj_b, x, nullptr, x1buf, BN_, 512, 512);
    ln_kernel<<<BN_, 128, 0, stream>>>(x1buf, ln2_w, ln2_b, h2buf);
    gemm_bt<1,128><<<dim3(2048/128, BN_/128), 256, 0, stream>>>(
        h2buf, fc1_wt, fc1_b, nullptr, ffbuf, nullptr, BN_, 2048, 512);
    gemm_bt<2,64><<<dim3(512/64, BN_/128), 256, 0, stream>>>(
        ffbuf, fc2_wt, fc2_b, x1buf, nullptr, out, BN_, 512, 2048);
}

// Round 11
// 287.504 us; speedup vs baseline: 1.0758x; 1.0474x over previous
//
#include <hip/hip_runtime.h>
#include <math.h>

typedef __bf16 bf16x8 __attribute__((ext_vector_type(8)));
typedef __bf16 bf16x4 __attribute__((ext_vector_type(4)));
typedef float  f32x4  __attribute__((ext_vector_type(4)));
typedef unsigned int u32x4 __attribute__((ext_vector_type(4)));

#define B_   2
#define N_   4096
#define D_   512
#define H_   8
#define FF_  2048
#define BN_  (B_*N_)
static constexpr float SCALE_ = 0.04419417382415922f;  // 512^-0.5
static constexpr float LOG2E_ = 1.44269504088896341f;
static constexpr float SCALE_L2E_ = SCALE_ * LOG2E_;   // fold log2e into Q scale

#define GLOAD_LDS16(g, l) __builtin_amdgcn_global_load_lds( \
    (const __attribute__((address_space(1))) void*)(g),     \
    (__attribute__((address_space(3))) void*)(l), 16, 0, 0)

// ---------------- weight transpose f32[R][C] -> bf16[C][R] ----------------
__global__ void transpose_to_bf16(const float* __restrict__ in, __bf16* __restrict__ out,
                                  int R, int C) {
    __shared__ float tile[32][33];
    const int c0 = blockIdx.x * 32, r0 = blockIdx.y * 32;
    const int tx = threadIdx.x, ty = threadIdx.y;   // (32,8)
#pragma unroll
    for (int i = 0; i < 4; ++i)
        tile[ty + 8*i][tx] = in[(size_t)(r0 + ty + 8*i) * C + c0 + tx];
    __syncthreads();
#pragma unroll
    for (int i = 0; i < 4; ++i)
        out[(size_t)(c0 + ty + 8*i) * R + r0 + tx] = (__bf16)tile[tx][ty + 8*i];
}

// ---------------- f32 -> bf16 elementwise (dist), folds log2e ----------------
__global__ void cvt_bf16(const float* __restrict__ in, __bf16* __restrict__ out, int n4) {
    int i = blockIdx.x * blockDim.x + threadIdx.x;
    const int stride = gridDim.x * blockDim.x;
    for (; i < n4; i += stride) {
        float4 v = ((const float4*)in)[i];
        bf16x4 o;
        o[0] = (__bf16)(v.x * LOG2E_); o[1] = (__bf16)(v.y * LOG2E_);
        o[2] = (__bf16)(v.z * LOG2E_); o[3] = (__bf16)(v.w * LOG2E_);
        ((bf16x4*)out)[i] = o;
    }
}

// ---------------- LayerNorm f32 -> bf16, one row (512) per block of 128 ----------------
__global__ __launch_bounds__(128)
void ln_kernel(const float* __restrict__ x, const float* __restrict__ w,
               const float* __restrict__ b, __bf16* __restrict__ out) {
    const int row = blockIdx.x, t = threadIdx.x;
    const float4 v = *(const float4*)&x[(size_t)row * 512 + t * 4];
    float s  = v.x + v.y + v.z + v.w;
    float sq = v.x*v.x + v.y*v.y + v.z*v.z + v.w*v.w;
#pragma unroll
    for (int mk = 1; mk < 64; mk <<= 1) { s += __shfl_xor(s, mk); sq += __shfl_xor(sq, mk); }
    __shared__ float ps[2][2];
    if ((t & 63) == 0) { ps[t >> 6][0] = s; ps[t >> 6][1] = sq; }
    __syncthreads();
    s = ps[0][0] + ps[1][0]; sq = ps[0][1] + ps[1][1];
    const float mu  = s * (1.0f / 512.0f);
    const float var = sq * (1.0f / 512.0f) - mu * mu;
    const float rs  = rsqrtf(var + 1e-5f);
    const float4 wv = *(const float4*)&w[t * 4];
    const float4 bv = *(const float4*)&b[t * 4];
    bf16x4 o;
    o[0] = (__bf16)((v.x - mu) * rs * wv.x + bv.x);
    o[1] = (__bf16)((v.y - mu) * rs * wv.y + bv.y);
    o[2] = (__bf16)((v.z - mu) * rs * wv.z + bv.z);
    o[3] = (__bf16)((v.w - mu) * rs * wv.w + bv.w);
    *(bf16x4*)&out[(size_t)row * 512 + t * 4] = o;
}

// ---------------- bf16 GEMM, C = A[M,K] * Bt[N,K]^T, fused epilogues ----------------
// EPI 0: +bias -> bf16 | EPI 1: +bias, exact gelu -> bf16 | EPI 2: +bias +resid(f32) -> f32
template<int EPI, int BNT>
__global__ __launch_bounds__(256)
void gemm_bt(const __bf16* __restrict__ A, const __bf16* __restrict__ Bt,
             const float* __restrict__ bias, const float* __restrict__ resid,
             __bf16* __restrict__ outb, float* __restrict__ outf,
             int M, int N, int K) {
    constexpr int NI = BNT / 32;                  // n-frags per wave (4 or 2)
    __shared__ __align__(16) __bf16 As[128 * 64];
    __shared__ __align__(16) __bf16 Bs[BNT * 64];
    const int tid = threadIdx.x;
    const int w = tid >> 6, l = tid & 63;
    const int g = l >> 4, c = l & 15;
    const int m0 = blockIdx.y * 128, n0 = blockIdx.x * BNT;
    const int wm = (w >> 1) * 64, wn = (w & 1) * (BNT / 2);
    f32x4 acc[4][NI] = {};

    for (int kt = 0; kt < K; kt += 64) {
        __syncthreads();
#pragma unroll
        for (int i = 0; i < 4; ++i) {             // A tile: 128x64
            const int cb = (i * 4 + w) * 64;      // wave-uniform chunk base
            const int chunk = cb + l;
            const int row = chunk >> 3, c8 = chunk & 7;
            GLOAD_LDS16(A + (size_t)(m0 + row) * K + kt + c8 * 8, As + cb * 8);
        }
#pragma unroll
        for (int i = 0; i < BNT / 32; ++i) {      // B tile: BNTx64
            const int cb = (i * 4 + w) * 64;
            const int chunk = cb + l;
            const int row = chunk >> 3, c8 = chunk & 7;
            GLOAD_LDS16(Bt + (size_t)(n0 + row) * K + kt + c8 * 8, Bs + cb * 8);
        }
        __syncthreads();
#pragma unroll
        for (int kk = 0; kk < 2; ++kk) {
            bf16x8 av[4], bv[NI];
#pragma unroll
            for (int mi = 0; mi < 4; ++mi)
                av[mi] = *(const bf16x8*)&As[(wm + mi * 16 + c) * 64 + kk * 32 + g * 8];
#pragma unroll
            for (int ni = 0; ni < NI; ++ni)
                bv[ni] = *(const bf16x8*)&Bs[(wn + ni * 16 + c) * 64 + kk * 32 + g * 8];
#pragma unroll
            for (int mi = 0; mi < 4; ++mi)
#pragma unroll
                for (int ni = 0; ni < NI; ++ni)
                    acc[mi][ni] = __builtin_amdgcn_mfma_f32_16x16x32_bf16(
                        av[mi], bv[ni], acc[mi][ni], 0, 0, 0);
        }
    }
#pragma unroll
    for (int mi = 0; mi < 4; ++mi)
#pragma unroll
        for (int ni = 0; ni < NI; ++ni)
#pragma unroll
            for (int r = 0; r < 4; ++r) {
                const int row = m0 + wm + mi * 16 + g * 4 + r;
                const int col = n0 + wn + ni * 16 + c;
                float v = acc[mi][ni][r] + bias[col];
                const size_t oidx = (size_t)row * N + col;
                if constexpr (EPI == 0) {
                    outb[oidx] = (__bf16)v;
                } else if constexpr (EPI == 1) {
                    outb[oidx] = (__bf16)(0.5f * v * (1.0f + erff(v * 0.70710678118654752f)));
                } else {
                    outf[oidx] = v + resid[oidx];
                }
            }
}

// ---------------- flash attention: 8 waves, ni-split key halves ----------------
// r10 base (proven: issue/latency-bound; ones-MFMA lsum, setprio, r7 schedule,
// FETCH 86MB clean). This rev re-partitions the SAME work across 8 waves (512
// threads): wave (wq=w&3, hn=w>>2) owns q-rows {64t+16wq+c} (t in-thread) and
// key tiles ni in {2hn, 2hn+1} only. Per-wave instruction stream HALVES while
// waves/SIMD doubles (2->4 chains to interleave); LDS read traffic unchanged
// (kf/vb/dd reads per thread halve). P-exchange is self-contained per half:
// pair (W[2hn],W[2hn+1]) -> pa[kk=hn], exactly the PV slice this wave needs.
// acc/accl are key-half partials -> one end-of-kernel LDS combine (hn=0 writes,
// hn=1 adds + finalizes). __launch_bounds__(512,4): 128-reg budget, ~100 live.
__global__ __launch_bounds__(512, 4)
void attn_kernel(const __bf16* __restrict__ qkv, const __bf16* __restrict__ distb,
                 const float* __restrict__ gamma, __bf16* __restrict__ outp) {
    __shared__ __align__(16) __bf16 Ks [64 * 64];      // K tile, linear + XOR swizzle
    __shared__ __align__(16) __bf16 Vts[64][72];       // V transposed, k XOR-swizzled
    __shared__ __align__(16) __bf16 DPs[2][128 * 64];  // dist double-buffer
    const int tid = threadIdx.x;
    const int w = tid >> 6, l = tid & 63;
    const int g = l >> 4, c = l & 15;
    const int wq = w & 3, hn = w >> 2;              // q-row group, key-half
    const int qt = blockIdx.x, h = blockIdx.y;
    const int b = blockIdx.z;
    const float gb = gamma[b];
    const size_t tok0 = (size_t)b * N_;
    const int qrow = 16 * wq + c;                   // lane's local q row (group 0)
    const int wub = tid & 448;                      // w*64, wave-uniform lds chunk base
    const int srow = tid >> 3;                      // staging row (0..63)
    const int sd0  = (tid & 7) * 8;                 // staging d-offset

    // Q fragments for both t-groups, pre-scaled by SCALE*log2e
    bf16x8 qf[2][2];
#pragma unroll
    for (int t = 0; t < 2; ++t) {
        const size_t qbase = (tok0 + qt * 128 + 64 * t + qrow) * 1536 + h * 64;
#pragma unroll
        for (int kk = 0; kk < 2; ++kk) {
            const bf16x8 qv = *(const bf16x8*)&qkv[qbase + kk * 32 + g * 8];
#pragma unroll
            for (int j = 0; j < 8; ++j) qf[t][kk][j] = (__bf16)((float)qv[j] * SCALE_L2E_);
        }
    }
    bf16x8 ones;
#pragma unroll
    for (int j = 0; j < 8; ++j) ones[j] = (__bf16)1.0f;

    f32x4 acc[2][4] = {};   // key-half partial: Onum[q=64t+qrow][d=16di+4g+r]
    f32x4 accl[2] = {};     // key-half partial softmax denominator
    bf16x8 vreg;

    auto issue_k = [&](int kt) {
        const int row = srow;
        const int col = ((tid & 7) ^ (row & 7)) * 8;       // source pre-swizzle
        GLOAD_LDS16(qkv + 512 + (tok0 + (size_t)kt * 64 + row) * 1536 + h * 64 + col,
                    Ks + wub * 8);
    };
    auto issue_d = [&](int kt, int buf) {
#pragma unroll
        for (int i = 0; i < 2; ++i) {
            const int row = i * 64 + srow;
            const int col = ((tid & 7) ^ (row & 7)) * 8;   // source pre-swizzle
            GLOAD_LDS16(distb + (size_t)(qt * 128 + row) * N_ + kt * 64 + col,
                        DPs[buf] + (i * 512 + wub) * 8);
        }
    };
    auto issue_v = [&](int kt) {
        vreg = *(const bf16x8*)
            &qkv[1024 + (tok0 + (size_t)kt * 64 + srow) * 1536 + h * 64 + sd0];
    };
    auto write_vts = [&]() {    // scalar transpose: vreg -> Vts
        const int kp = srow ^ sd0;   // sd0 = (sd0>>3)<<3 here
#pragma unroll
        for (int j = 0; j < 8; ++j) Vts[sd0 + j][kp] = vreg[j];
    };

    const int ktend = N_ / 64;                      // 64 tiles, all keys
    issue_k(0);
    issue_v(0);
    issue_d(0, 0);

    for (int kt = 0; kt < ktend; ++kt) {
        const int cur = kt & 1;
        __syncthreads();     // B1: full drain -- K/V/dist(kt) landed, PV(kt-1) done
        write_vts();
        if (kt + 1 < ktend) {    // vreg dead, DPs[cur^1] dead since B3(kt-1)
            issue_v(kt + 1);
            issue_d(kt + 1, cur ^ 1);
        }
        __builtin_amdgcn_sched_barrier(0);

        // QK^T + fused softmax for this wave's key-half: ni = 2*hn + nii
        uint32_t W[2][2][2];
#pragma unroll
        for (int nii = 0; nii < 2; ++nii) {
            const int ni = 2 * hn + nii;
            f32x4 s0 = {}, s1 = {};
            __builtin_amdgcn_s_setprio(1);
#pragma unroll
            for (int kk = 0; kk < 2; ++kk) {
                const bf16x8 kf = *(const bf16x8*)
                    &Ks[((16 * ni + c) << 6) + ((kk * 32 + g * 8) ^ ((c & 7) << 3))];
                s0 = __builtin_amdgcn_mfma_f32_16x16x32_bf16(kf, qf[0][kk], s0, 0, 0, 0);
                s1 = __builtin_amdgcn_mfma_f32_16x16x32_bf16(kf, qf[1][kk], s1, 0, 0, 0);
            }
            __builtin_amdgcn_s_setprio(0);
#pragma unroll
            for (int t = 0; t < 2; ++t) {
                const int row = 64 * t + qrow;
                const bf16x4 dd = *(const bf16x4*)
                    &DPs[cur][(row << 6) + ((16 * ni + 4 * g) ^ ((c & 7) << 3))];
                const f32x4 sv = (t == 0) ? s0 : s1;
                float pv0, pv1, pv2, pv3;
                pv0 = __builtin_amdgcn_exp2f(fmaf(-gb, (float)dd[0], sv[0]));
                pv1 = __builtin_amdgcn_exp2f(fmaf(-gb, (float)dd[1], sv[1]));
                pv2 = __builtin_amdgcn_exp2f(fmaf(-gb, (float)dd[2], sv[2]));
                pv3 = __builtin_amdgcn_exp2f(fmaf(-gb, (float)dd[3], sv[3]));
                asm("v_cvt_pk_bf16_f32 %0, %1, %2" : "=v"(W[t][nii][0]) : "v"(pv0), "v"(pv1));
                asm("v_cvt_pk_bf16_f32 %0, %1, %2" : "=v"(W[t][nii][1]) : "v"(pv2), "v"(pv3));
            }
        }
        // P-word exchange within the half: (W[nii=0],W[nii=1]) -> pa[kk=hn]
        bf16x8 pa[2];
#pragma unroll
        for (int t = 0; t < 2; ++t) {
#pragma unroll
            for (int p = 0; p < 2; ++p) {
                asm("v_permlane32_swap_b32 %0, %1"
                    : "+v"(W[t][0][p]), "+v"(W[t][1][p]));
                asm("v_permlane16_swap_b32 %0, %1"
                    : "+v"(W[t][0][p]), "+v"(W[t][1][p]));
            }
            const u32x4 words = {W[t][0][0], W[t][0][1], W[t][1][0], W[t][1][1]};
            pa[t] = __builtin_bit_cast(bf16x8, words);
        }
        __builtin_amdgcn_sched_barrier(0);
        // B3: own LDS ops drained (Ks/DPs reads, Vts writes) + block barrier.
        asm volatile("s_waitcnt lgkmcnt(0)\n\ts_barrier" ::: "memory");
        __builtin_amdgcn_sched_barrier(0);
        if (kt + 1 < ktend) issue_k(kt + 1);   // Ks free now; flies across PV

        // PV over this wave's key-half (kk = hn); lsum via ones-MFMA
        __builtin_amdgcn_s_setprio(1);
        accl[0] = __builtin_amdgcn_mfma_f32_16x16x32_bf16(ones, pa[0], accl[0], 0, 0, 0);
        accl[1] = __builtin_amdgcn_mfma_f32_16x16x32_bf16(ones, pa[1], accl[1], 0, 0, 0);
#pragma unroll
        for (int di = 0; di < 4; ++di) {
            const int d = 16 * di + c;
            const int kp = (hn * 32 + g * 8) ^ ((d >> 3) << 3);
            const bf16x8 vb = *(const bf16x8*)&Vts[d][kp];
            acc[0][di] = __builtin_amdgcn_mfma_f32_16x16x32_bf16(vb, pa[0], acc[0][di], 0, 0, 0);
            acc[1][di] = __builtin_amdgcn_mfma_f32_16x16x32_bf16(vb, pa[1], acc[1][di], 0, 0, 0);
        }
        __builtin_amdgcn_s_setprio(0);
    }

    // combine the two key-halves (hn=0 writes partials, hn=1 adds + finalizes)
    __syncthreads();
    float* sacc = (float*)&DPs[0][0];      // 256 slots x 8 f32x4 = 32KB
    float* sl   = (float*)&Ks[0];          // 256 slots x 2 f32
    const int slot = wq * 64 + l;
    if (hn == 0) {
#pragma unroll
        for (int t = 0; t < 2; ++t) {
            sl[slot * 2 + t] = accl[t][0];
#pragma unroll
            for (int di = 0; di < 4; ++di)
                *(f32x4*)&sacc[(slot * 8 + t * 4 + di) * 4] = acc[t][di];
        }
    }
    __syncthreads();
    if (hn == 1) {
#pragma unroll
        for (int t = 0; t < 2; ++t) {
            const float rl = 1.0f / (accl[t][0] + sl[slot * 2 + t]);
            const int q = qt * 128 + 64 * t + qrow;
#pragma unroll
            for (int di = 0; di < 4; ++di) {
                const f32x4 oa = acc[t][di] + *(const f32x4*)&sacc[(slot * 8 + t * 4 + di) * 4];
                bf16x4 o;
#pragma unroll
                for (int r = 0; r < 4; ++r) o[r] = (__bf16)(oa[r] * rl);
                *(bf16x4*)&outp[((size_t)(b * N_ + q)) * 512 + h * 64 + 16 * di + 4 * g] = o;
            }
        }
    }
}

// ---------------- launch ----------------
extern "C" void kernel_launch(void* const* d_in, const int* in_sizes, int n_in,
                              void* d_out, int out_size, void* d_ws, size_t ws_size,
                              hipStream_t stream) {
    (void)in_sizes; (void)n_in; (void)out_size; (void)ws_size;
    const float* x      = (const float*)d_in[0];
    const float* gamma  = (const float*)d_in[1];
    const float* dist   = (const float*)d_in[2];
    const float* ln1_w  = (const float*)d_in[3];
    const float* ln1_b  = (const float*)d_in[4];
    const float* qkv_w  = (const float*)d_in[5];
    const float* qkv_b  = (const float*)d_in[6];
    const float* proj_w = (const float*)d_in[7];
    const float* proj_b = (const float*)d_in[8];
    const float* ln2_w  = (const float*)d_in[9];
    const float* ln2_b  = (const float*)d_in[10];
    const float* fc1_w  = (const float*)d_in[11];
    const float* fc1_b  = (const float*)d_in[12];
    const float* fc2_w  = (const float*)d_in[13];
    const float* fc2_b  = (const float*)d_in[14];
    float* out = (float*)d_out;

    char* ws = (char*)d_ws;
    size_t off = 0;
    auto alloc = [&](size_t bytes) {
        void* p = ws + off; off = (off + bytes + 255) & ~(size_t)255; return p;
    };
    __bf16* distbf  = (__bf16*)alloc((size_t)N_ * N_ * 2);
    __bf16* qkv_wt  = (__bf16*)alloc((size_t)1536 * 512 * 2);
    __bf16* proj_wt = (__bf16*)alloc((size_t)512 * 512 * 2);
    __bf16* fc1_wt  = (__bf16*)alloc((size_t)2048 * 512 * 2);
    __bf16* fc2_wt  = (__bf16*)alloc((size_t)512 * 2048 * 2);
    __bf16* hbuf    = (__bf16*)alloc((size_t)BN_ * 512 * 2);
    __bf16* qkvbuf  = (__bf16*)alloc((size_t)BN_ * 1536 * 2);
    __bf16* attnbuf = (__bf16*)alloc((size_t)BN_ * 512 * 2);
    float*  x1buf   = (float*) alloc((size_t)BN_ * 512 * 4);
    __bf16* h2buf   = (__bf16*)alloc((size_t)BN_ * 512 * 2);
    __bf16* ffbuf   = (__bf16*)alloc((size_t)BN_ * 2048 * 2);

    const dim3 tb(32, 8);
    transpose_to_bf16<<<dim3(1536/32,  512/32), tb, 0, stream>>>(qkv_w,  qkv_wt,  512, 1536);
    transpose_to_bf16<<<dim3( 512/32,  512/32), tb, 0, stream>>>(proj_w, proj_wt, 512,  512);
    transpose_to_bf16<<<dim3(2048/32,  512/32), tb, 0, stream>>>(fc1_w,  fc1_wt,  512, 2048);
    transpose_to_bf16<<<dim3( 512/32, 2048/32), tb, 0, stream>>>(fc2_w,  fc2_wt, 2048,  512);
    cvt_bf16<<<2048, 256, 0, stream>>>(dist, distbf, N_ * N_ / 4);

    ln_kernel<<<BN_, 128, 0, stream>>>(x, ln1_w, ln1_b, hbuf);
    gemm_bt<0,128><<<dim3(1536/128, BN_/128), 256, 0, stream>>>(
        hbuf, qkv_wt, qkv_b, nullptr, qkvbuf, nullptr, BN_, 1536, 512);
    attn_kernel<<<dim3(32, 8, 2), 512, 0, stream>>>(qkvbuf, distbf, gamma, attnbuf);
    gemm_bt<2,64><<<dim3(512/64, BN_/128), 256, 0, stream>>>(
        attnbuf, proj_wt, proj_b, x, nullptr, x1buf, BN_, 512, 512);
    ln_kernel<<<BN_, 128, 0, stream>>>(x1buf, ln2_w, ln2_b, h2buf);
    gemm_bt<1,128><<<dim3(2048/128, BN_/128), 256, 0, stream>>>(
        h2buf, fc1_wt, fc1_b, nullptr, ffbuf, nullptr, BN_, 2048, 512);
    gemm_bt<2,64><<<dim3(512/64, BN_/128), 256, 0, stream>>>(
        ffbuf, fc2_wt, fc2_b, x1buf, nullptr, out, BN_, 512, 2048);
}

// Round 12
// 283.263 us; speedup vs baseline: 1.0919x; 1.0150x over previous
//
#include <hip/hip_runtime.h>
#include <math.h>

typedef __bf16 bf16x8 __attribute__((ext_vector_type(8)));
typedef __bf16 bf16x4 __attribute__((ext_vector_type(4)));
typedef float  f32x4  __attribute__((ext_vector_type(4)));
typedef unsigned int u32x4 __attribute__((ext_vector_type(4)));

#define B_   2
#define N_   4096
#define D_   512
#define H_   8
#define FF_  2048
#define BN_  (B_*N_)
static constexpr float SCALE_ = 0.04419417382415922f;  // 512^-0.5
static constexpr float LOG2E_ = 1.44269504088896341f;
static constexpr float SCALE_L2E_ = SCALE_ * LOG2E_;   // fold log2e into Q scale

#define GLOAD_LDS16(g, l) __builtin_amdgcn_global_load_lds( \
    (const __attribute__((address_space(1))) void*)(g),     \
    (__attribute__((address_space(3))) void*)(l), 16, 0, 0)

// ---------------- weight transpose f32[R][C] -> bf16[C][R] ----------------
__global__ void transpose_to_bf16(const float* __restrict__ in, __bf16* __restrict__ out,
                                  int R, int C) {
    __shared__ float tile[32][33];
    const int c0 = blockIdx.x * 32, r0 = blockIdx.y * 32;
    const int tx = threadIdx.x, ty = threadIdx.y;   // (32,8)
#pragma unroll
    for (int i = 0; i < 4; ++i)
        tile[ty + 8*i][tx] = in[(size_t)(r0 + ty + 8*i) * C + c0 + tx];
    __syncthreads();
#pragma unroll
    for (int i = 0; i < 4; ++i)
        out[(size_t)(c0 + ty + 8*i) * R + r0 + tx] = (__bf16)tile[tx][ty + 8*i];
}

// ---------------- f32 -> bf16 elementwise (dist), folds log2e ----------------
__global__ void cvt_bf16(const float* __restrict__ in, __bf16* __restrict__ out, int n4) {
    int i = blockIdx.x * blockDim.x + threadIdx.x;
    const int stride = gridDim.x * blockDim.x;
    for (; i < n4; i += stride) {
        float4 v = ((const float4*)in)[i];
        bf16x4 o;
        o[0] = (__bf16)(v.x * LOG2E_); o[1] = (__bf16)(v.y * LOG2E_);
        o[2] = (__bf16)(v.z * LOG2E_); o[3] = (__bf16)(v.w * LOG2E_);
        ((bf16x4*)out)[i] = o;
    }
}

// ---------------- LayerNorm f32 -> bf16, one row (512) per block of 128 ----------------
__global__ __launch_bounds__(128)
void ln_kernel(const float* __restrict__ x, const float* __restrict__ w,
               const float* __restrict__ b, __bf16* __restrict__ out) {
    const int row = blockIdx.x, t = threadIdx.x;
    const float4 v = *(const float4*)&x[(size_t)row * 512 + t * 4];
    float s  = v.x + v.y + v.z + v.w;
    float sq = v.x*v.x + v.y*v.y + v.z*v.z + v.w*v.w;
#pragma unroll
    for (int mk = 1; mk < 64; mk <<= 1) { s += __shfl_xor(s, mk); sq += __shfl_xor(sq, mk); }
    __shared__ float ps[2][2];
    if ((t & 63) == 0) { ps[t >> 6][0] = s; ps[t >> 6][1] = sq; }
    __syncthreads();
    s = ps[0][0] + ps[1][0]; sq = ps[0][1] + ps[1][1];
    const float mu  = s * (1.0f / 512.0f);
    const float var = sq * (1.0f / 512.0f) - mu * mu;
    const float rs  = rsqrtf(var + 1e-5f);
    const float4 wv = *(const float4*)&w[t * 4];
    const float4 bv = *(const float4*)&b[t * 4];
    bf16x4 o;
    o[0] = (__bf16)((v.x - mu) * rs * wv.x + bv.x);
    o[1] = (__bf16)((v.y - mu) * rs * wv.y + bv.y);
    o[2] = (__bf16)((v.z - mu) * rs * wv.z + bv.z);
    o[3] = (__bf16)((v.w - mu) * rs * wv.w + bv.w);
    *(bf16x4*)&out[(size_t)row * 512 + t * 4] = o;
}

// ---------------- bf16 GEMM, C = A[M,K] * Bt[N,K]^T, fused epilogues ----------------
// EPI 0: +bias -> bf16 | EPI 1: +bias, exact gelu -> bf16 | EPI 2: +bias +resid(f32) -> f32
template<int EPI, int BNT>
__global__ __launch_bounds__(256)
void gemm_bt(const __bf16* __restrict__ A, const __bf16* __restrict__ Bt,
             const float* __restrict__ bias, const float* __restrict__ resid,
             __bf16* __restrict__ outb, float* __restrict__ outf,
             int M, int N, int K) {
    constexpr int NI = BNT / 32;                  // n-frags per wave (4 or 2)
    __shared__ __align__(16) __bf16 As[128 * 64];
    __shared__ __align__(16) __bf16 Bs[BNT * 64];
    const int tid = threadIdx.x;
    const int w = tid >> 6, l = tid & 63;
    const int g = l >> 4, c = l & 15;
    const int m0 = blockIdx.y * 128, n0 = blockIdx.x * BNT;
    const int wm = (w >> 1) * 64, wn = (w & 1) * (BNT / 2);
    f32x4 acc[4][NI] = {};

    for (int kt = 0; kt < K; kt += 64) {
        __syncthreads();
#pragma unroll
        for (int i = 0; i < 4; ++i) {             // A tile: 128x64
            const int cb = (i * 4 + w) * 64;      // wave-uniform chunk base
            const int chunk = cb + l;
            const int row = chunk >> 3, c8 = chunk & 7;
            GLOAD_LDS16(A + (size_t)(m0 + row) * K + kt + c8 * 8, As + cb * 8);
        }
#pragma unroll
        for (int i = 0; i < BNT / 32; ++i) {      // B tile: BNTx64
            const int cb = (i * 4 + w) * 64;
            const int chunk = cb + l;
            const int row = chunk >> 3, c8 = chunk & 7;
            GLOAD_LDS16(Bt + (size_t)(n0 + row) * K + kt + c8 * 8, Bs + cb * 8);
        }
        __syncthreads();
#pragma unroll
        for (int kk = 0; kk < 2; ++kk) {
            bf16x8 av[4], bv[NI];
#pragma unroll
            for (int mi = 0; mi < 4; ++mi)
                av[mi] = *(const bf16x8*)&As[(wm + mi * 16 + c) * 64 + kk * 32 + g * 8];
#pragma unroll
            for (int ni = 0; ni < NI; ++ni)
                bv[ni] = *(const bf16x8*)&Bs[(wn + ni * 16 + c) * 64 + kk * 32 + g * 8];
#pragma unroll
            for (int mi = 0; mi < 4; ++mi)
#pragma unroll
                for (int ni = 0; ni < NI; ++ni)
                    acc[mi][ni] = __builtin_amdgcn_mfma_f32_16x16x32_bf16(
                        av[mi], bv[ni], acc[mi][ni], 0, 0, 0);
        }
    }
#pragma unroll
    for (int mi = 0; mi < 4; ++mi)
#pragma unroll
        for (int ni = 0; ni < NI; ++ni)
#pragma unroll
            for (int r = 0; r < 4; ++r) {
                const int row = m0 + wm + mi * 16 + g * 4 + r;
                const int col = n0 + wn + ni * 16 + c;
                float v = acc[mi][ni][r] + bias[col];
                const size_t oidx = (size_t)row * N + col;
                if constexpr (EPI == 0) {
                    outb[oidx] = (__bf16)v;
                } else if constexpr (EPI == 1) {
                    outb[oidx] = (__bf16)(0.5f * v * (1.0f + erff(v * 0.70710678118654752f)));
                } else {
                    outf[oidx] = v + resid[oidx];
                }
            }
}

// ---------------- flash attention: 8 waves, ni-split key halves ----------------
// r11 base (proven: issue/latency-bound; ni-split 8 waves, ones-MFMA lsum,
// setprio, r7 schedule, fused combine). This rev deletes per-iteration
// instructions without touching the schedule:
//  * strength-reduced addressing: issue lambdas are zero-arg with running
//    global pointers (gk/gv/gd += stride) -- no per-iter 64-bit remultiply.
//  * dist bias folded into the QK MFMA C-input: s = mfma(..., Cin=-gb*dd),
//    exp2 consumes the MFMA result directly. The cvt+mul for Cin are
//    MFMA-independent and issue during the MFMA latency window. Numerically
//    identical modulo f32 accumulation order.
__global__ __launch_bounds__(512, 4)
void attn_kernel(const __bf16* __restrict__ qkv, const __bf16* __restrict__ distb,
                 const float* __restrict__ gamma, __bf16* __restrict__ outp) {
    __shared__ __align__(16) __bf16 Ks [64 * 64];      // K tile, linear + XOR swizzle
    __shared__ __align__(16) __bf16 Vts[64][72];       // V transposed, k XOR-swizzled
    __shared__ __align__(16) __bf16 DPs[2][128 * 64];  // dist double-buffer
    const int tid = threadIdx.x;
    const int w = tid >> 6, l = tid & 63;
    const int g = l >> 4, c = l & 15;
    const int wq = w & 3, hn = w >> 2;              // q-row group, key-half
    const int qt = blockIdx.x, h = blockIdx.y;
    const int b = blockIdx.z;
    const float gb = gamma[b];
    const size_t tok0 = (size_t)b * N_;
    const int qrow = 16 * wq + c;                   // lane's local q row (group 0)
    const int wub = tid & 448;                      // w*64, wave-uniform lds chunk base
    const int srow = tid >> 3;                      // staging row (0..63)
    const int sd0  = (tid & 7) * 8;                 // staging d-offset
    const int cswz = ((tid & 7) ^ (srow & 7)) * 8;  // source pre-swizzle col
    const int swz  = (c & 7) << 3;                  // LDS read swizzle

    // Q fragments for both t-groups, pre-scaled by SCALE*log2e
    bf16x8 qf[2][2];
#pragma unroll
    for (int t = 0; t < 2; ++t) {
        const size_t qbase = (tok0 + qt * 128 + 64 * t + qrow) * 1536 + h * 64;
#pragma unroll
        for (int kk = 0; kk < 2; ++kk) {
            const bf16x8 qv = *(const bf16x8*)&qkv[qbase + kk * 32 + g * 8];
#pragma unroll
            for (int j = 0; j < 8; ++j) qf[t][kk][j] = (__bf16)((float)qv[j] * SCALE_L2E_);
        }
    }
    bf16x8 ones;
#pragma unroll
    for (int j = 0; j < 8; ++j) ones[j] = (__bf16)1.0f;

    f32x4 acc[2][4] = {};   // key-half partial: Onum[q=64t+qrow][d=16di+4g+r]
    f32x4 accl[2] = {};     // key-half partial softmax denominator
    bf16x8 vreg;

    // running global pointers (strength-reduced: advance by constant stride)
    const size_t kvstep = (size_t)64 * 1536;
    const __bf16* gk = qkv + 512  + (tok0 + srow) * 1536 + h * 64 + cswz;
    const __bf16* gv = qkv + 1024 + (tok0 + srow) * 1536 + h * 64 + sd0;
    const __bf16* gd = distb + (size_t)(qt * 128 + srow) * N_ + cswz;

    auto issue_k = [&]() {
        GLOAD_LDS16(gk, Ks + wub * 8);
        gk += kvstep;
    };
    auto issue_d = [&](int buf) {
        GLOAD_LDS16(gd,                    DPs[buf] + wub * 8);
        GLOAD_LDS16(gd + (size_t)64 * N_,  DPs[buf] + (512 + wub) * 8);
        gd += 64;
    };
    auto issue_v = [&]() {
        vreg = *(const bf16x8*)gv;
        gv += kvstep;
    };
    auto write_vts = [&]() {    // scalar transpose: vreg -> Vts
        const int kp = srow ^ sd0;   // sd0 = (sd0>>3)<<3 here
#pragma unroll
        for (int j = 0; j < 8; ++j) Vts[sd0 + j][kp] = vreg[j];
    };

    const int ktend = N_ / 64;                      // 64 tiles, all keys
    issue_k();
    issue_v();
    issue_d(0);

    for (int kt = 0; kt < ktend; ++kt) {
        const int cur = kt & 1;
        __syncthreads();     // B1: full drain -- K/V/dist(kt) landed, PV(kt-1) done
        write_vts();
        if (kt + 1 < ktend) {    // vreg dead, DPs[cur^1] dead since B3(kt-1)
            issue_v();
            issue_d(cur ^ 1);
        }
        __builtin_amdgcn_sched_barrier(0);

        // QK^T for this wave's key-half, dist bias as MFMA C-input
        uint32_t W[2][2][2];
#pragma unroll
        for (int nii = 0; nii < 2; ++nii) {
            const int ni = 2 * hn + nii;
            f32x4 s0, s1;
            {   // Cin = -gb * dd  (independent of MFMA; fills its latency window)
                const bf16x4 dd0 = *(const bf16x4*)
                    &DPs[cur][(qrow << 6) + ((16 * ni + 4 * g) ^ swz)];
                const bf16x4 dd1 = *(const bf16x4*)
                    &DPs[cur][((64 + qrow) << 6) + ((16 * ni + 4 * g) ^ swz)];
#pragma unroll
                for (int r = 0; r < 4; ++r) {
                    s0[r] = -gb * (float)dd0[r];
                    s1[r] = -gb * (float)dd1[r];
                }
            }
            __builtin_amdgcn_s_setprio(1);
#pragma unroll
            for (int kk = 0; kk < 2; ++kk) {
                const bf16x8 kf = *(const bf16x8*)
                    &Ks[((16 * ni + c) << 6) + ((kk * 32 + g * 8) ^ swz)];
                s0 = __builtin_amdgcn_mfma_f32_16x16x32_bf16(kf, qf[0][kk], s0, 0, 0, 0);
                s1 = __builtin_amdgcn_mfma_f32_16x16x32_bf16(kf, qf[1][kk], s1, 0, 0, 0);
            }
            __builtin_amdgcn_s_setprio(0);
#pragma unroll
            for (int t = 0; t < 2; ++t) {
                const f32x4 sv = (t == 0) ? s0 : s1;
                float pv0, pv1, pv2, pv3;
                pv0 = __builtin_amdgcn_exp2f(sv[0]);
                pv1 = __builtin_amdgcn_exp2f(sv[1]);
                pv2 = __builtin_amdgcn_exp2f(sv[2]);
                pv3 = __builtin_amdgcn_exp2f(sv[3]);
                asm("v_cvt_pk_bf16_f32 %0, %1, %2" : "=v"(W[t][nii][0]) : "v"(pv0), "v"(pv1));
                asm("v_cvt_pk_bf16_f32 %0, %1, %2" : "=v"(W[t][nii][1]) : "v"(pv2), "v"(pv3));
            }
        }
        // P-word exchange within the half: (W[nii=0],W[nii=1]) -> pa[kk=hn]
        bf16x8 pa[2];
#pragma unroll
        for (int t = 0; t < 2; ++t) {
#pragma unroll
            for (int p = 0; p < 2; ++p) {
                asm("v_permlane32_swap_b32 %0, %1"
                    : "+v"(W[t][0][p]), "+v"(W[t][1][p]));
                asm("v_permlane16_swap_b32 %0, %1"
                    : "+v"(W[t][0][p]), "+v"(W[t][1][p]));
            }
            const u32x4 words = {W[t][0][0], W[t][0][1], W[t][1][0], W[t][1][1]};
            pa[t] = __builtin_bit_cast(bf16x8, words);
        }
        __builtin_amdgcn_sched_barrier(0);
        // B3: own LDS ops drained (Ks/DPs reads, Vts writes) + block barrier.
        asm volatile("s_waitcnt lgkmcnt(0)\n\ts_barrier" ::: "memory");
        __builtin_amdgcn_sched_barrier(0);
        if (kt + 1 < ktend) issue_k();   // Ks free now; flies across PV

        // PV over this wave's key-half (kk = hn); lsum via ones-MFMA
        __builtin_amdgcn_s_setprio(1);
        accl[0] = __builtin_amdgcn_mfma_f32_16x16x32_bf16(ones, pa[0], accl[0], 0, 0, 0);
        accl[1] = __builtin_amdgcn_mfma_f32_16x16x32_bf16(ones, pa[1], accl[1], 0, 0, 0);
#pragma unroll
        for (int di = 0; di < 4; ++di) {
            const int d = 16 * di + c;
            const int kp = (hn * 32 + g * 8) ^ ((d >> 3) << 3);
            const bf16x8 vb = *(const bf16x8*)&Vts[d][kp];
            acc[0][di] = __builtin_amdgcn_mfma_f32_16x16x32_bf16(vb, pa[0], acc[0][di], 0, 0, 0);
            acc[1][di] = __builtin_amdgcn_mfma_f32_16x16x32_bf16(vb, pa[1], acc[1][di], 0, 0, 0);
        }
        __builtin_amdgcn_s_setprio(0);
    }

    // combine the two key-halves (hn=0 writes partials, hn=1 adds + finalizes)
    __syncthreads();
    float* sacc = (float*)&DPs[0][0];      // 256 slots x 8 f32x4 = 32KB
    float* sl   = (float*)&Ks[0];          // 256 slots x 2 f32
    const int slot = wq * 64 + l;
    if (hn == 0) {
#pragma unroll
        for (int t = 0; t < 2; ++t) {
            sl[slot * 2 + t] = accl[t][0];
#pragma unroll
            for (int di = 0; di < 4; ++di)
                *(f32x4*)&sacc[(slot * 8 + t * 4 + di) * 4] = acc[t][di];
        }
    }
    __syncthreads();
    if (hn == 1) {
#pragma unroll
        for (int t = 0; t < 2; ++t) {
            const float rl = 1.0f / (accl[t][0] + sl[slot * 2 + t]);
            const int q = qt * 128 + 64 * t + qrow;
#pragma unroll
            for (int di = 0; di < 4; ++di) {
                const f32x4 oa = acc[t][di] + *(const f32x4*)&sacc[(slot * 8 + t * 4 + di) * 4];
                bf16x4 o;
#pragma unroll
                for (int r = 0; r < 4; ++r) o[r] = (__bf16)(oa[r] * rl);
                *(bf16x4*)&outp[((size_t)(b * N_ + q)) * 512 + h * 64 + 16 * di + 4 * g] = o;
            }
        }
    }
}

// ---------------- launch ----------------
extern "C" void kernel_launch(void* const* d_in, const int* in_sizes, int n_in,
                              void* d_out, int out_size, void* d_ws, size_t ws_size,
                              hipStream_t stream) {
    (void)in_sizes; (void)n_in; (void)out_size; (void)ws_size;
    const float* x      = (const float*)d_in[0];
    const float* gamma  = (const float*)d_in[1];
    const float* dist   = (const float*)d_in[2];
    const float* ln1_w  = (const float*)d_in[3];
    const float* ln1_b  = (const float*)d_in[4];
    const float* qkv_w  = (const float*)d_in[5];
    const float* qkv_b  = (const float*)d_in[6];
    const float* proj_w = (const float*)d_in[7];
    const float* proj_b = (const float*)d_in[8];
    const float* ln2_w  = (const float*)d_in[9];
    const float* ln2_b  = (const float*)d_in[10];
    const float* fc1_w  = (const float*)d_in[11];
    const float* fc1_b  = (const float*)d_in[12];
    const float* fc2_w  = (const float*)d_in[13];
    const float* fc2_b  = (const float*)d_in[14];
    float* out = (float*)d_out;

    char* ws = (char*)d_ws;
    size_t off = 0;
    auto alloc = [&](size_t bytes) {
        void* p = ws + off; off = (off + bytes + 255) & ~(size_t)255; return p;
    };
    __bf16* distbf  = (__bf16*)alloc((size_t)N_ * N_ * 2);
    __bf16* qkv_wt  = (__bf16*)alloc((size_t)1536 * 512 * 2);
    __bf16* proj_wt = (__bf16*)alloc((size_t)512 * 512 * 2);
    __bf16* fc1_wt  = (__bf16*)alloc((size_t)2048 * 512 * 2);
    __bf16* fc2_wt  = (__bf16*)alloc((size_t)512 * 2048 * 2);
    __bf16* hbuf    = (__bf16*)alloc((size_t)BN_ * 512 * 2);
    __bf16* qkvbuf  = (__bf16*)alloc((size_t)BN_ * 1536 * 2);
    __bf16* attnbuf = (__bf16*)alloc((size_t)BN_ * 512 * 2);
    float*  x1buf   = (float*) alloc((size_t)BN_ * 512 * 4);
    __bf16* h2buf   = (__bf16*)alloc((size_t)BN_ * 512 * 2);
    __bf16* ffbuf   = (__bf16*)alloc((size_t)BN_ * 2048 * 2);

    const dim3 tb(32, 8);
    transpose_to_bf16<<<dim3(1536/32,  512/32), tb, 0, stream>>>(qkv_w,  qkv_wt,  512, 1536);
    transpose_to_bf16<<<dim3( 512/32,  512/32), tb, 0, stream>>>(proj_w, proj_wt, 512,  512);
    transpose_to_bf16<<<dim3(2048/32,  512/32), tb, 0, stream>>>(fc1_w,  fc1_wt,  512, 2048);
    transpose_to_bf16<<<dim3( 512/32, 2048/32), tb, 0, stream>>>(fc2_w,  fc2_wt, 2048,  512);
    cvt_bf16<<<2048, 256, 0, stream>>>(dist, distbf, N_ * N_ / 4);

    ln_kernel<<<BN_, 128, 0, stream>>>(x, ln1_w, ln1_b, hbuf);
    gemm_bt<0,128><<<dim3(1536/128, BN_/128), 256, 0, stream>>>(
        hbuf, qkv_wt, qkv_b, nullptr, qkvbuf, nullptr, BN_, 1536, 512);
    attn_kernel<<<dim3(32, 8, 2), 512, 0, stream>>>(qkvbuf, distbf, gamma, attnbuf);
    gemm_bt<2,64><<<dim3(512/64, BN_/128), 256, 0, stream>>>(
        attnbuf, proj_wt, proj_b, x, nullptr, x1buf, BN_, 512, 512);
    ln_kernel<<<BN_, 128, 0, stream>>>(x1buf, ln2_w, ln2_b, h2buf);
    gemm_bt<1,128><<<dim3(2048/128, BN_/128), 256, 0, stream>>>(
        h2buf, fc1_wt, fc1_b, nullptr, ffbuf, nullptr, BN_, 2048, 512);
    gemm_bt<2,64><<<dim3(512/64, BN_/128), 256, 0, stream>>>(
        ffbuf, fc2_wt, fc2_b, x1buf, nullptr, out, BN_, 512, 2048);
}